// Round 6
// baseline (242.357 us; speedup 1.0000x reference)
//
#include <hip/hip_runtime.h>
#include <math.h>

#define N_NODES 100000
#define N_EDGES 1600000
#define CHUNK 4096
#define NCH ((N_EDGES + CHUNK - 1) / CHUNK)   // 391 chunks of edges
#define DSH 9                                  // 512 nodes per dst bucket
#define NBD ((N_NODES + 511) / 512)            // 196 dst buckets
#define CAP 9216                               // fixed bucket capacity (mean 8163, sigma~90)
#define RCAP 10240                             // k_rank LDS edge capacity

typedef __attribute__((ext_vector_type(8))) short bf16x8;   // 8 bf16 = 4 VGPRs
typedef __attribute__((ext_vector_type(4))) float f32x4;
typedef __attribute__((ext_vector_type(2))) float f32x2;

union U4S8 { uint4 u; bf16x8 s; };

// ---- bf16 pack helpers (RNE) ----
__device__ inline unsigned pk_bf16(float a, float b) {
    unsigned ua = __float_as_uint(a), ub = __float_as_uint(b);
    ua = (ua + 0x7FFFu + ((ua >> 16) & 1u)) >> 16;
    ub = (ub + 0x7FFFu + ((ub >> 16) & 1u)) >> 16;
    return (ua & 0xFFFFu) | (ub << 16);
}
__device__ inline unsigned short bf16_1(float a) {
    unsigned ua = __float_as_uint(a);
    return (unsigned short)((ua + 0x7FFFu + ((ua >> 16) & 1u)) >> 16);
}

// fp8 e4m3 decode-accumulate: uint2 (8 fp8) -> 4 packed-f32 accumulators
__device__ inline void acc8_fp8(f32x2* a, uint2 v) {
    a[0] += __builtin_amdgcn_cvt_pk_f32_fp8((int)v.x, false);
    a[1] += __builtin_amdgcn_cvt_pk_f32_fp8((int)v.x, true);
    a[2] += __builtin_amdgcn_cvt_pk_f32_fp8((int)v.y, false);
    a[3] += __builtin_amdgcn_cvt_pk_f32_fp8((int)v.y, true);
}

// async global->LDS DMA, 16 B per lane, single vmcnt queue, no VGPR round-trip
__device__ inline void gload_lds16(const void* g, void* l) {
    __builtin_amdgcn_global_load_lds(
        (const __attribute__((address_space(1))) unsigned*)g,
        (__attribute__((address_space(3))) unsigned*)l, 16, 0, 0);
}

// ---------------- weight prep + dummy rows + gtails zero ----------------

__global__ __launch_bounds__(256) void k_prep(const float* __restrict__ W1, const float* __restrict__ W2,
                                              unsigned* __restrict__ W1t, unsigned* __restrict__ W2t,
                                              unsigned* __restrict__ Hb, unsigned* __restrict__ H2b,
                                              int* __restrict__ gtails) {
    __shared__ short L[16384];
    int t = threadIdx.x;
    if (blockIdx.x == 0) {
        if (t < NBD) gtails[t] = 0;               // replaces hipMemsetAsync dispatch
        for (int i = t; i < 16384; i += 256) {
            int k = i >> 7, n = i & 127;
            L[n * 128 + k] = (short)bf16_1(W1[i]);
        }
        __syncthreads();
        uint4* out = (uint4*)W1t;
        const uint4* src = (const uint4*)L;
        for (int i = t; i < 2048; i += 256) out[i] = src[i];
        if (t < 32) Hb[(size_t)N_NODES * 32 + t] = 0u;    // fp8 dummy row = 32 uints
    } else {
        for (int i = t; i < 48 * 128; i += 256) L[i] = 0;
        __syncthreads();
        for (int i = t; i < 5120; i += 256) {
            int k = i / 40, n = i - k * 40;
            L[n * 128 + k] = (short)bf16_1(W2[i]);
        }
        __syncthreads();
        uint4* out = (uint4*)W2t;
        const uint4* src = (const uint4*)L;
        for (int i = t; i < 768; i += 256) out[i] = src[i];
        if (t < 10) H2b[(size_t)N_NODES * 10 + t] = 0u;   // fp8 dummy row = 10 uints
    }
}

// ---------------- CSR build: 2 kernels, fixed-capacity buckets ----------------
// int4-vectorized edge reads (4 edges/thread/iter) in both passes.

__global__ __launch_bounds__(256) void k_partD(const int* __restrict__ src, const int* __restrict__ dst,
                                               int* __restrict__ gtails, unsigned* __restrict__ staged, int E) {
    __shared__ int hist[NBD];
    __shared__ int tails[NBD];
    int t = threadIdx.x, c = blockIdx.x;
    if (t < NBD) hist[t] = 0;
    __syncthreads();
    int be = c * CHUNK, cw = min(CHUNK, E - be);   // cw % 4 == 0 always (E % 4 == 0, CHUNK % 4 == 0)
    int cw4 = cw >> 2;
    const int4* d4 = (const int4*)(dst + be);
    const int4* s4 = (const int4*)(src + be);
    for (int l = t; l < cw4; l += 256) {
        int4 d = d4[l];
        atomicAdd(&hist[d.x >> DSH], 1);
        atomicAdd(&hist[d.y >> DSH], 1);
        atomicAdd(&hist[d.z >> DSH], 1);
        atomicAdd(&hist[d.w >> DSH], 1);
    }
    __syncthreads();
    if (t < NBD) tails[t] = t * CAP + atomicAdd(&gtails[t], hist[t]);
    __syncthreads();
    for (int l = t; l < cw4; l += 256) {
        int4 d = d4[l];
        int4 s = s4[l];
        int i0 = atomicAdd(&tails[d.x >> DSH], 1);
        staged[i0] = ((unsigned)s.x << DSH) | (unsigned)(d.x & 511);
        int i1 = atomicAdd(&tails[d.y >> DSH], 1);
        staged[i1] = ((unsigned)s.y << DSH) | (unsigned)(d.y & 511);
        int i2 = atomicAdd(&tails[d.z >> DSH], 1);
        staged[i2] = ((unsigned)s.z << DSH) | (unsigned)(d.z & 511);
        int i3 = atomicAdd(&tails[d.w >> DSH], 1);
        staged[i3] = ((unsigned)s.w << DSH) | (unsigned)(d.w & 511);
    }
}

__global__ __launch_bounds__(256) void k_rank(const unsigned* __restrict__ staged, const int* __restrict__ gtails,
                                              int* __restrict__ csr, int* __restrict__ rowptr,
                                              int* __restrict__ cnt, float* __restrict__ dinv, int N) {
    __shared__ unsigned ebuf[RCAP];
    __shared__ int deg[512];
    __shared__ int sc[256];
    __shared__ int tails[512];
    int b = blockIdx.x, t = threadIdx.x;
    int n0 = b << DSH;
    int eb = b * CAP;                 // CAP*4 bytes = 36864*b -> 16-B aligned
    int ne = gtails[b];
    deg[t] = 0; deg[t + 256] = 0;
    __syncthreads();
    bool fit = (ne <= RCAP);
    if (fit) {
        int ne4 = ne >> 2;
        const uint4* st4 = (const uint4*)(staged + eb);
        for (int l = t; l < ne4; l += 256) {
            uint4 pr = st4[l];
            ((uint4*)ebuf)[l] = pr;
            atomicAdd(&deg[pr.x & 511], 1);
            atomicAdd(&deg[pr.y & 511], 1);
            atomicAdd(&deg[pr.z & 511], 1);
            atomicAdd(&deg[pr.w & 511], 1);
        }
        for (int l = (ne4 << 2) + t; l < ne; l += 256) {
            unsigned pr = staged[eb + l];
            ebuf[l] = pr;
            atomicAdd(&deg[pr & 511], 1);
        }
    } else {
        for (int l = t; l < ne; l += 256)
            atomicAdd(&deg[staged[eb + l] & 511], 1);
    }
    __syncthreads();
    int d0 = deg[2 * t], d1 = deg[2 * t + 1];
    int ts = d0 + d1;
    sc[t] = ts; __syncthreads();
    for (int o = 1; o < 256; o <<= 1) {
        int v = (t >= o) ? sc[t - o] : 0;
        __syncthreads();
        sc[t] += v;
        __syncthreads();
    }
    int excl = sc[t] - ts;
    int na = n0 + 2 * t, nb = n0 + 2 * t + 1;
    tails[2 * t] = eb + excl;
    tails[2 * t + 1] = eb + excl + d0;
    if (na < N) { rowptr[na] = eb + excl;      cnt[na] = d0; dinv[na] = rsqrtf((float)(d0 + 1)); }
    if (nb < N) { rowptr[nb] = eb + excl + d0; cnt[nb] = d1; dinv[nb] = rsqrtf((float)(d1 + 1)); }
    __syncthreads();
    if (fit) {
        int ne4 = ne >> 2;
        for (int l = t; l < ne4; l += 256) {
            uint4 pr = ((const uint4*)ebuf)[l];
            int p0 = atomicAdd(&tails[pr.x & 511], 1); csr[p0] = (int)(pr.x >> DSH);
            int p1 = atomicAdd(&tails[pr.y & 511], 1); csr[p1] = (int)(pr.y >> DSH);
            int p2 = atomicAdd(&tails[pr.z & 511], 1); csr[p2] = (int)(pr.z >> DSH);
            int p3 = atomicAdd(&tails[pr.w & 511], 1); csr[p3] = (int)(pr.w >> DSH);
        }
        for (int l = (ne4 << 2) + t; l < ne; l += 256) {
            unsigned pr = ebuf[l];
            int pos = atomicAdd(&tails[pr & 511], 1);
            csr[pos] = (int)(pr >> DSH);
        }
    } else {
        for (int l = t; l < ne; l += 256) {
            unsigned pr = staged[eb + l];
            int pos = atomicAdd(&tails[pr & 511], 1);
            csr[pos] = (int)(pr >> DSH);
        }
    }
}

// ---------------- GEMM 1 (MFMA): Hb = fp8e4m3((x @ W1) * dinv[row]) ----------------
// PERSISTENT grid-stride blocks. B (32 KB) staged once per block; A double-buffered
// (2 x 32 KB): issue next tile's async DMA burst, compute current tile, ONE barrier
// per tile (prefetch lands under the compute+epilogue). Row-XOR swizzled granules.

__global__ __launch_bounds__(256) void k_gemm1(const float* __restrict__ x, const unsigned* __restrict__ W1t,
                                               const float* __restrict__ dinv, unsigned* __restrict__ Hb, int M) {
    __shared__ uint4 Bs[2048];      // 32 KB
    __shared__ uint4 As[2][2048];   // 2 x 32 KB
    int t = threadIdx.x;
    int w = t >> 6, lane = t & 63;
    int m = lane & 15, kg = lane >> 4;
    const int NT = (M + 63) >> 6;
    const int GRID = (int)gridDim.x;

    // stage B once (L2-hot table)
    #pragma unroll
    for (int it = 0; it < 8; ++it) {
        int G = it * 256 + t;
        int rb = G >> 4, slot = G & 15;
        gload_lds16(W1t + rb * 64 + ((slot ^ (rb & 7)) << 2), (char*)Bs + (size_t)G * 16);
    }
    // stage first A tile
    int tix = blockIdx.x;
    if (tix < NT) {
        #pragma unroll
        for (int it = 0; it < 8; ++it) {
            int G = it * 256 + t;
            int row = G >> 5, slot = G & 31;
            int rowg = min(tix * 64 + row, M - 1);
            gload_lds16(x + (size_t)rowg * 128 + ((slot ^ (row & 7)) << 2), (char*)As[0] + (size_t)G * 16);
        }
    }
    __syncthreads();   // drain all prologue DMAs

    int ra = (w << 4) + m;
    int rs = m & 7;
    int cur = 0;
    for (; tix < NT; tix += GRID) {
        int tn = tix + GRID;
        if (tn < NT) {   // prefetch next tile into the other buffer
            #pragma unroll
            for (int it = 0; it < 8; ++it) {
                int G = it * 256 + t;
                int row = G >> 5, slot = G & 31;
                int rowg = min(tn * 64 + row, M - 1);
                gload_lds16(x + (size_t)rowg * 128 + ((slot ^ (row & 7)) << 2),
                            (char*)As[cur ^ 1] + (size_t)G * 16);
            }
        }

        f32x4 acc[8];
        #pragma unroll
        for (int j = 0; j < 8; j++) acc[j] = (f32x4){0.f, 0.f, 0.f, 0.f};

        const uint4* Ac = As[cur];
        #pragma unroll
        for (int ks = 0; ks < 4; ks++) {
            uint4 qa = Ac[ra * 32 + ((ks * 8 + kg * 2) ^ rs)];
            uint4 qb = Ac[ra * 32 + ((ks * 8 + kg * 2 + 1) ^ rs)];
            float4 f0 = *(float4*)&qa;
            float4 f1 = *(float4*)&qb;
            U4S8 a0; a0.u = make_uint4(pk_bf16(f0.x, f0.y), pk_bf16(f0.z, f0.w),
                                       pk_bf16(f1.x, f1.y), pk_bf16(f1.z, f1.w));
            #pragma unroll
            for (int nt = 0; nt < 8; nt++) {
                U4S8 b; b.u = Bs[(nt * 16 + m) * 16 + ((ks * 4 + kg) ^ rs)];
                acc[nt] = __builtin_amdgcn_mfma_f32_16x16x32_bf16(a0.s, b.s, acc[nt], 0, 0, 0);
            }
        }
        // C layout: col = lane&15, row = kg*4 + reg. Pack 4 adjacent cols -> 1 uint of fp8.
        int m_base = tix * 64 + (w << 4);
        #pragma unroll
        for (int r = 0; r < 4; r++) {
            int row = m_base + kg * 4 + r;
            float di = dinv[min(row, M - 1)];
            bool on = (row < M) && ((m & 3) == 0);
            #pragma unroll
            for (int nt = 0; nt < 8; nt++) {
                float v = acc[nt][r] * di;
                float v1 = __shfl_xor(v, 1);
                unsigned wlo = (unsigned)__builtin_amdgcn_cvt_pk_fp8_f32(v, v1, 0, false);
                unsigned whi = __shfl_xor(wlo, 2);
                unsigned u = (wlo & 0xFFFFu) | (whi << 16);
                if (on) Hb[(size_t)row * 32 + nt * 4 + (m >> 2)] = u;
            }
        }
        __syncthreads();   // drains prefetch DMAs; all waves done reading As[cur]
        cur ^= 1;
    }
}

// ---------------- Propagation 1: h1b = bf16(relu(dinv[i]*(self + sum_nb) + b1)) ----------------
// ONE node per 16-lane group (4 nodes/wave). Each lane owns 8 features end-to-end.
// 8-deep gather unroll: 8 outstanding 128-B row fetches per group.

__global__ __launch_bounds__(256) void k_prop1(const unsigned* __restrict__ Hb, const int* __restrict__ rowptr,
                                               const int* __restrict__ cnt, const int* __restrict__ csr,
                                               const float* __restrict__ dinv, const float* __restrict__ b1,
                                               unsigned* __restrict__ h1b, int N) {
    int lane = threadIdx.x & 63;
    int g = lane >> 4, q = lane & 15;
    int i = blockIdx.x * 16 + (threadIdx.x >> 6) * 4 + g;
    if (i >= N) return;
    const uint2* H2 = (const uint2*)Hb;    // row = 16 x uint2 (128 B fp8)

    f32x2 a0[4], a1[4], a2[4], a3[4];
    #pragma unroll
    for (int k = 0; k < 4; k++) {
        a0[k] = (f32x2){0.f, 0.f}; a1[k] = (f32x2){0.f, 0.f};
        a2[k] = (f32x2){0.f, 0.f}; a3[k] = (f32x2){0.f, 0.f};
    }

    // self row
    {
        uint2 sv = H2[(size_t)i * 16 + q];
        acc8_fp8(a0, sv);
    }

    int s = rowptr[i];
    int e = s + cnt[i];
    int p = s;
    for (; p + 8 <= e; p += 8) {
        int j0 = csr[p];     int j1 = csr[p + 1];
        int j2 = csr[p + 2]; int j3 = csr[p + 3];
        int j4 = csr[p + 4]; int j5 = csr[p + 5];
        int j6 = csr[p + 6]; int j7 = csr[p + 7];
        uint2 v0 = H2[(size_t)j0 * 16 + q];
        uint2 v1 = H2[(size_t)j1 * 16 + q];
        uint2 v2 = H2[(size_t)j2 * 16 + q];
        uint2 v3 = H2[(size_t)j3 * 16 + q];
        uint2 v4 = H2[(size_t)j4 * 16 + q];
        uint2 v5 = H2[(size_t)j5 * 16 + q];
        uint2 v6 = H2[(size_t)j6 * 16 + q];
        uint2 v7 = H2[(size_t)j7 * 16 + q];
        acc8_fp8(a0, v0); acc8_fp8(a1, v1); acc8_fp8(a2, v2); acc8_fp8(a3, v3);
        acc8_fp8(a0, v4); acc8_fp8(a1, v5); acc8_fp8(a2, v6); acc8_fp8(a3, v7);
    }
    if (p + 4 <= e) {
        int j0 = csr[p];     int j1 = csr[p + 1];
        int j2 = csr[p + 2]; int j3 = csr[p + 3];
        uint2 v0 = H2[(size_t)j0 * 16 + q];
        uint2 v1 = H2[(size_t)j1 * 16 + q];
        uint2 v2 = H2[(size_t)j2 * 16 + q];
        uint2 v3 = H2[(size_t)j3 * 16 + q];
        acc8_fp8(a0, v0); acc8_fp8(a1, v1); acc8_fp8(a2, v2); acc8_fp8(a3, v3);
        p += 4;
    }
    for (; p < e; ++p) {                    // 0..3 leftover edges (exec-masked divergence)
        int j = csr[p];
        uint2 v = H2[(size_t)j * 16 + q];
        acc8_fp8(a0, v);
    }
    #pragma unroll
    for (int k = 0; k < 4; k++) a0[k] = (a0[k] + a1[k]) + (a2[k] + a3[k]);

    float di = dinv[i];
    float4 bA = ((const float4*)b1)[q * 2];
    float4 bB = ((const float4*)b1)[q * 2 + 1];
    float o0 = fmaxf(di * a0[0].x + bA.x, 0.f);
    float o1 = fmaxf(di * a0[0].y + bA.y, 0.f);
    float o2 = fmaxf(di * a0[1].x + bA.z, 0.f);
    float o3 = fmaxf(di * a0[1].y + bA.w, 0.f);
    float o4 = fmaxf(di * a0[2].x + bB.x, 0.f);
    float o5 = fmaxf(di * a0[2].y + bB.y, 0.f);
    float o6 = fmaxf(di * a0[3].x + bB.z, 0.f);
    float o7 = fmaxf(di * a0[3].y + bB.w, 0.f);
    ((uint4*)h1b)[(size_t)i * 16 + q] =
        make_uint4(pk_bf16(o0, o1), pk_bf16(o2, o3), pk_bf16(o4, o5), pk_bf16(o6, o7));
}

// ---------------- GEMM 2 (MFMA): H2b = fp8e4m3((h1 @ W2) * dinv[row]), 40-B rows ----------------
// Same persistent double-buffered structure as k_gemm1 (B 12 KB once, A 2 x 16 KB).

__global__ __launch_bounds__(256) void k_gemm2(const unsigned* __restrict__ h1b, const unsigned* __restrict__ W2t,
                                               const float* __restrict__ dinv, unsigned* __restrict__ H2b, int M) {
    __shared__ uint4 Bs[768];       // 12 KB
    __shared__ uint4 As[2][1024];   // 2 x 16 KB
    int t = threadIdx.x;
    int w = t >> 6, lane = t & 63;
    int m = lane & 15, kg = lane >> 4;
    const int NT = (M + 63) >> 6;
    const int GRID = (int)gridDim.x;

    #pragma unroll
    for (int it = 0; it < 3; ++it) {
        int G = it * 256 + t;
        int rb = G >> 4, slot = G & 15;
        gload_lds16(W2t + rb * 64 + ((slot ^ (rb & 7)) << 2), (char*)Bs + (size_t)G * 16);
    }
    int tix = blockIdx.x;
    if (tix < NT) {
        #pragma unroll
        for (int it = 0; it < 4; ++it) {
            int G = it * 256 + t;
            int row = G >> 4, slot = G & 15;
            int rowg = min(tix * 64 + row, M - 1);
            gload_lds16(h1b + (size_t)rowg * 64 + ((slot ^ (row & 7)) << 2), (char*)As[0] + (size_t)G * 16);
        }
    }
    __syncthreads();

    int ra = (w << 4) + m;
    int rs = m & 7;
    int cur = 0;
    for (; tix < NT; tix += GRID) {
        int tn = tix + GRID;
        if (tn < NT) {
            #pragma unroll
            for (int it = 0; it < 4; ++it) {
                int G = it * 256 + t;
                int row = G >> 4, slot = G & 15;
                int rowg = min(tn * 64 + row, M - 1);
                gload_lds16(h1b + (size_t)rowg * 64 + ((slot ^ (row & 7)) << 2),
                            (char*)As[cur ^ 1] + (size_t)G * 16);
            }
        }

        f32x4 acc[3];
        #pragma unroll
        for (int j = 0; j < 3; j++) acc[j] = (f32x4){0.f, 0.f, 0.f, 0.f};

        const uint4* Ac = As[cur];
        #pragma unroll
        for (int ks = 0; ks < 4; ks++) {
            U4S8 a0; a0.u = Ac[ra * 16 + ((ks * 4 + kg) ^ rs)];
            #pragma unroll
            for (int nt = 0; nt < 3; nt++) {
                U4S8 b; b.u = Bs[(nt * 16 + m) * 16 + ((ks * 4 + kg) ^ rs)];
                acc[nt] = __builtin_amdgcn_mfma_f32_16x16x32_bf16(a0.s, b.s, acc[nt], 0, 0, 0);
            }
        }
        // pack 8 adjacent cols -> uint2 of fp8; row = 5 uint2 (40 B)
        int m_base = tix * 64 + (w << 4);
        #pragma unroll
        for (int r = 0; r < 4; r++) {
            int row = m_base + kg * 4 + r;
            float di = dinv[min(row, M - 1)];
            #pragma unroll
            for (int nt = 0; nt < 3; nt++) {
                float v = acc[nt][r] * di;
                float v1 = __shfl_xor(v, 1);
                unsigned wlo = (unsigned)__builtin_amdgcn_cvt_pk_fp8_f32(v, v1, 0, false);
                unsigned whi = __shfl_xor(wlo, 2);
                unsigned u = (wlo & 0xFFFFu) | (whi << 16);
                unsigned u2 = __shfl_xor(u, 4);
                bool on = (row < M) && ((m & 7) == 0) && (nt < 2 || m == 0);
                if (on) ((uint2*)H2b)[(size_t)row * 5 + nt * 2 + (m >> 3)] = make_uint2(u, u2);
            }
        }
        __syncthreads();
        cur ^= 1;
    }
}

// ---------------- Propagation 2 + bias + log_softmax -> out ----------------
// ONE node per 5-lane group (12 nodes/wave, lanes 60-63 idle). Each lane owns
// 8 of the 40 features end-to-end; 8-deep gather unroll.

__global__ __launch_bounds__(256) void k_prop2(const unsigned* __restrict__ H2b, const int* __restrict__ rowptr,
                                               const int* __restrict__ cnt, const int* __restrict__ csr,
                                               const float* __restrict__ dinv, const float* __restrict__ b2,
                                               float* __restrict__ out, int N) {
    int lane = threadIdx.x & 63;
    int wv = threadIdx.x >> 6;
    int grp = lane / 5;              // 0..11 active; 12 for lanes 60-63
    int q = lane - grp * 5;          // 0..4
    if (grp >= 12) return;
    int i = blockIdx.x * 48 + wv * 12 + grp;
    if (i >= N) return;              // group-uniform exit (all 5 lanes same i)
    const uint2* H2 = (const uint2*)H2b;   // row = 5 uint2 (40 B)

    f32x2 a0[4], a1[4], a2[4], a3[4];
    #pragma unroll
    for (int k = 0; k < 4; k++) {
        a0[k] = (f32x2){0.f, 0.f}; a1[k] = (f32x2){0.f, 0.f};
        a2[k] = (f32x2){0.f, 0.f}; a3[k] = (f32x2){0.f, 0.f};
    }

    // self row
    acc8_fp8(a0, H2[(size_t)i * 5 + q]);

    int s = rowptr[i];
    int e = s + cnt[i];
    int p = s;
    for (; p + 8 <= e; p += 8) {
        int j0 = csr[p];     int j1 = csr[p + 1];
        int j2 = csr[p + 2]; int j3 = csr[p + 3];
        int j4 = csr[p + 4]; int j5 = csr[p + 5];
        int j6 = csr[p + 6]; int j7 = csr[p + 7];
        uint2 v0 = H2[(size_t)j0 * 5 + q];
        uint2 v1 = H2[(size_t)j1 * 5 + q];
        uint2 v2 = H2[(size_t)j2 * 5 + q];
        uint2 v3 = H2[(size_t)j3 * 5 + q];
        uint2 v4 = H2[(size_t)j4 * 5 + q];
        uint2 v5 = H2[(size_t)j5 * 5 + q];
        uint2 v6 = H2[(size_t)j6 * 5 + q];
        uint2 v7 = H2[(size_t)j7 * 5 + q];
        acc8_fp8(a0, v0); acc8_fp8(a1, v1); acc8_fp8(a2, v2); acc8_fp8(a3, v3);
        acc8_fp8(a0, v4); acc8_fp8(a1, v5); acc8_fp8(a2, v6); acc8_fp8(a3, v7);
    }
    if (p + 4 <= e) {
        int j0 = csr[p];     int j1 = csr[p + 1];
        int j2 = csr[p + 2]; int j3 = csr[p + 3];
        uint2 v0 = H2[(size_t)j0 * 5 + q];
        uint2 v1 = H2[(size_t)j1 * 5 + q];
        uint2 v2 = H2[(size_t)j2 * 5 + q];
        uint2 v3 = H2[(size_t)j3 * 5 + q];
        acc8_fp8(a0, v0); acc8_fp8(a1, v1); acc8_fp8(a2, v2); acc8_fp8(a3, v3);
        p += 4;
    }
    for (; p < e; ++p) {
        uint2 v = H2[(size_t)csr[p] * 5 + q];
        acc8_fp8(a0, v);
    }
    #pragma unroll
    for (int k = 0; k < 4; k++) a0[k] = (a0[k] + a1[k]) + (a2[k] + a3[k]);

    float di = dinv[i];
    float4 b0 = ((const float4*)b2)[q * 2];
    float4 b1v = ((const float4*)b2)[q * 2 + 1];
    float l[8];
    l[0] = di * a0[0].x + b0.x;  l[1] = di * a0[0].y + b0.y;
    l[2] = di * a0[1].x + b0.z;  l[3] = di * a0[1].y + b0.w;
    l[4] = di * a0[2].x + b1v.x; l[5] = di * a0[2].y + b1v.y;
    l[6] = di * a0[3].x + b1v.z; l[7] = di * a0[3].y + b1v.w;

    // local max over 8, then 5-lane group max via +1,+2,+4 (mod 5) tree
    float mx = l[0];
    #pragma unroll
    for (int k = 1; k < 8; k++) mx = fmaxf(mx, l[k]);
    int gb = grp * 5;
    mx = fmaxf(mx, __shfl(mx, gb + (q + 1) % 5));
    mx = fmaxf(mx, __shfl(mx, gb + (q + 2) % 5));
    mx = fmaxf(mx, __shfl(mx, gb + (q + 4) % 5));

    float sm = 0.f;
    #pragma unroll
    for (int k = 0; k < 8; k++) sm += expf(l[k] - mx);
    // 5-lane sum: gather the 4 other lanes' partial sums directly
    float st = sm;
    st += __shfl(sm, gb + (q + 1) % 5);
    st += __shfl(sm, gb + (q + 2) % 5);
    st += __shfl(sm, gb + (q + 3) % 5);
    st += __shfl(sm, gb + (q + 4) % 5);
    float lse = mx + logf(st);

    ((float4*)out)[(size_t)i * 10 + q * 2]     = make_float4(l[0] - lse, l[1] - lse, l[2] - lse, l[3] - lse);
    ((float4*)out)[(size_t)i * 10 + q * 2 + 1] = make_float4(l[4] - lse, l[5] - lse, l[6] - lse, l[7] - lse);
}

// ---------------- launch ----------------

extern "C" void kernel_launch(void* const* d_in, const int* in_sizes, int n_in,
                              void* d_out, int out_size, void* d_ws, size_t ws_size,
                              hipStream_t stream) {
    const float* x  = (const float*)d_in[0];
    const int*   ei = (const int*)d_in[1];
    const float* W1 = (const float*)d_in[2];
    const float* b1 = (const float*)d_in[3];
    const float* W2 = (const float*)d_in[4];
    const float* b2 = (const float*)d_in[5];
    float* out = (float*)d_out;
    char* ws = (char*)d_ws;
    const int N = N_NODES, E = N_EDGES;

    size_t o = 0;
    auto alloc = [&](size_t bytes) { size_t cur = o; o += (bytes + 511) & ~(size_t)511; return cur; };
    int*       cnt    = (int*)(ws + alloc((size_t)N * 4));
    int*       rowptr = (int*)(ws + alloc((size_t)N * 4));
    float*     dinv   = (float*)(ws + alloc((size_t)N * 4));
    int*       gtails = (int*)(ws + alloc((size_t)NBD * 4));
    unsigned*  staged = (unsigned*)(ws + alloc((size_t)NBD * CAP * 4));
    int*       csr    = (int*)(ws + alloc((size_t)NBD * CAP * 4));
    unsigned*  W1t    = (unsigned*)(ws + alloc(128 * 128 * 2));             // bf16 [128][128]
    unsigned*  W2t    = (unsigned*)(ws + alloc(48 * 128 * 2));              // bf16 [48][128]
    unsigned*  Hb     = (unsigned*)(ws + alloc((size_t)(N + 1) * 32 * 4));  // fp8 [N+1,128]
    unsigned*  h1b    = (unsigned*)(ws + alloc((size_t)N * 64 * 4));        // bf16 [N,128]
    unsigned*  H2b    = (unsigned*)(ws + alloc((size_t)(N + 1) * 10 * 4));  // fp8 [N+1,40]

    const int* src = ei;
    const int* dst = ei + E;

    k_prep <<<2, 256, 0, stream>>>(W1, W2, W1t, W2t, Hb, H2b, gtails);
    k_partD<<<NCH, 256, 0, stream>>>(src, dst, gtails, staged, E);
    k_rank <<<NBD, 256, 0, stream>>>(staged, gtails, csr, rowptr, cnt, dinv, N);

    k_gemm1<<<256, 256, 0, stream>>>(x, W1t, dinv, Hb, N);     // persistent, 1 block/CU (96 KB LDS)
    k_prop1<<<(N + 15) / 16, 256, 0, stream>>>(Hb, rowptr, cnt, csr, dinv, b1, h1b, N);
    k_gemm2<<<512, 256, 0, stream>>>(h1b, W2t, dinv, H2b, N);  // persistent, 2 blocks/CU (44 KB LDS)
    k_prop2<<<(N + 47) / 48, 256, 0, stream>>>(H2b, rowptr, cnt, csr, dinv, b2, out, N);

    (void)in_sizes; (void)n_in; (void)out_size; (void)ws_size;
}

// Round 7
// 224.057 us; speedup vs baseline: 1.0817x; 1.0817x over previous
//
#include <hip/hip_runtime.h>
#include <math.h>

#define N_NODES 100000
#define N_EDGES 1600000
#define CHUNK 4096
#define NCH ((N_EDGES + CHUNK - 1) / CHUNK)   // 391 chunks of edges
#define DSH 9                                  // 512 nodes per dst bucket
#define NBD ((N_NODES + 511) / 512)            // 196 dst buckets
#define CAP 9216                               // fixed bucket capacity (mean 8163, sigma~90)
#define RCAP 10240                             // k_rank LDS edge capacity

typedef __attribute__((ext_vector_type(8))) short bf16x8;   // 8 bf16 = 4 VGPRs
typedef __attribute__((ext_vector_type(4))) float f32x4;
typedef __attribute__((ext_vector_type(2))) float f32x2;

union U4S8 { uint4 u; bf16x8 s; };

// ---- bf16 pack helpers (RNE) ----
__device__ inline unsigned pk_bf16(float a, float b) {
    unsigned ua = __float_as_uint(a), ub = __float_as_uint(b);
    ua = (ua + 0x7FFFu + ((ua >> 16) & 1u)) >> 16;
    ub = (ub + 0x7FFFu + ((ub >> 16) & 1u)) >> 16;
    return (ua & 0xFFFFu) | (ub << 16);
}
__device__ inline unsigned short bf16_1(float a) {
    unsigned ua = __float_as_uint(a);
    return (unsigned short)((ua + 0x7FFFu + ((ua >> 16) & 1u)) >> 16);
}

// fp8 e4m3 decode-accumulate: uint2 (8 fp8) -> 4 packed-f32 accumulators
__device__ inline void acc8_fp8(f32x2* a, uint2 v) {
    a[0] += __builtin_amdgcn_cvt_pk_f32_fp8((int)v.x, false);
    a[1] += __builtin_amdgcn_cvt_pk_f32_fp8((int)v.x, true);
    a[2] += __builtin_amdgcn_cvt_pk_f32_fp8((int)v.y, false);
    a[3] += __builtin_amdgcn_cvt_pk_f32_fp8((int)v.y, true);
}

// async global->LDS DMA, 16 B per lane, single vmcnt queue, no VGPR round-trip
__device__ inline void gload_lds16(const void* g, void* l) {
    __builtin_amdgcn_global_load_lds(
        (const __attribute__((address_space(1))) unsigned*)g,
        (__attribute__((address_space(3))) unsigned*)l, 16, 0, 0);
}

// ---------------- weight prep + dummy rows + gtails zero ----------------

__global__ __launch_bounds__(256) void k_prep(const float* __restrict__ W1, const float* __restrict__ W2,
                                              unsigned* __restrict__ W1t, unsigned* __restrict__ W2t,
                                              unsigned* __restrict__ Hb, unsigned* __restrict__ H2b,
                                              int* __restrict__ gtails) {
    __shared__ short L[16384];
    int t = threadIdx.x;
    if (blockIdx.x == 0) {
        if (t < NBD) gtails[t] = 0;               // replaces hipMemsetAsync dispatch
        for (int i = t; i < 16384; i += 256) {
            int k = i >> 7, n = i & 127;
            L[n * 128 + k] = (short)bf16_1(W1[i]);
        }
        __syncthreads();
        uint4* out = (uint4*)W1t;
        const uint4* src = (const uint4*)L;
        for (int i = t; i < 2048; i += 256) out[i] = src[i];
        if (t < 32) Hb[(size_t)N_NODES * 32 + t] = 0u;    // fp8 dummy row = 32 uints
    } else {
        for (int i = t; i < 48 * 128; i += 256) L[i] = 0;
        __syncthreads();
        for (int i = t; i < 5120; i += 256) {
            int k = i / 40, n = i - k * 40;
            L[n * 128 + k] = (short)bf16_1(W2[i]);
        }
        __syncthreads();
        uint4* out = (uint4*)W2t;
        const uint4* src = (const uint4*)L;
        for (int i = t; i < 768; i += 256) out[i] = src[i];
        if (t < 10) H2b[(size_t)N_NODES * 10 + t] = 0u;   // fp8 dummy row = 10 uints
    }
}

// ---------------- CSR build: 2 kernels, fixed-capacity buckets ----------------
// int4-vectorized edge reads (4 edges/thread/iter) in both passes.

__global__ __launch_bounds__(256) void k_partD(const int* __restrict__ src, const int* __restrict__ dst,
                                               int* __restrict__ gtails, unsigned* __restrict__ staged, int E) {
    __shared__ int hist[NBD];
    __shared__ int tails[NBD];
    int t = threadIdx.x, c = blockIdx.x;
    if (t < NBD) hist[t] = 0;
    __syncthreads();
    int be = c * CHUNK, cw = min(CHUNK, E - be);   // cw % 4 == 0 always (E % 4 == 0, CHUNK % 4 == 0)
    int cw4 = cw >> 2;
    const int4* d4 = (const int4*)(dst + be);
    const int4* s4 = (const int4*)(src + be);
    for (int l = t; l < cw4; l += 256) {
        int4 d = d4[l];
        atomicAdd(&hist[d.x >> DSH], 1);
        atomicAdd(&hist[d.y >> DSH], 1);
        atomicAdd(&hist[d.z >> DSH], 1);
        atomicAdd(&hist[d.w >> DSH], 1);
    }
    __syncthreads();
    if (t < NBD) tails[t] = t * CAP + atomicAdd(&gtails[t], hist[t]);
    __syncthreads();
    for (int l = t; l < cw4; l += 256) {
        int4 d = d4[l];
        int4 s = s4[l];
        int i0 = atomicAdd(&tails[d.x >> DSH], 1);
        staged[i0] = ((unsigned)s.x << DSH) | (unsigned)(d.x & 511);
        int i1 = atomicAdd(&tails[d.y >> DSH], 1);
        staged[i1] = ((unsigned)s.y << DSH) | (unsigned)(d.y & 511);
        int i2 = atomicAdd(&tails[d.z >> DSH], 1);
        staged[i2] = ((unsigned)s.z << DSH) | (unsigned)(d.z & 511);
        int i3 = atomicAdd(&tails[d.w >> DSH], 1);
        staged[i3] = ((unsigned)s.w << DSH) | (unsigned)(d.w & 511);
    }
}

// per bucket: degree count -> wave-shuffle scan (2 barriers, was 16) -> csr fill
__global__ __launch_bounds__(256) void k_rank(const unsigned* __restrict__ staged, const int* __restrict__ gtails,
                                              int* __restrict__ csr, int* __restrict__ rowptr,
                                              int* __restrict__ cnt, float* __restrict__ dinv, int N) {
    __shared__ unsigned ebuf[RCAP];
    __shared__ int deg[512];
    __shared__ int tails[512];
    __shared__ int wsum[4];
    int b = blockIdx.x, t = threadIdx.x;
    int lane = t & 63, wv = t >> 6;
    int n0 = b << DSH;
    int eb = b * CAP;                 // CAP*4 bytes = 36864*b -> 16-B aligned
    int ne = gtails[b];
    deg[t] = 0; deg[t + 256] = 0;
    __syncthreads();
    bool fit = (ne <= RCAP);
    if (fit) {
        int ne4 = ne >> 2;
        const uint4* st4 = (const uint4*)(staged + eb);
        for (int l = t; l < ne4; l += 256) {
            uint4 pr = st4[l];
            ((uint4*)ebuf)[l] = pr;
            atomicAdd(&deg[pr.x & 511], 1);
            atomicAdd(&deg[pr.y & 511], 1);
            atomicAdd(&deg[pr.z & 511], 1);
            atomicAdd(&deg[pr.w & 511], 1);
        }
        for (int l = (ne4 << 2) + t; l < ne; l += 256) {
            unsigned pr = staged[eb + l];
            ebuf[l] = pr;
            atomicAdd(&deg[pr & 511], 1);
        }
    } else {
        for (int l = t; l < ne; l += 256)
            atomicAdd(&deg[staged[eb + l] & 511], 1);
    }
    __syncthreads();
    int d0 = deg[2 * t], d1 = deg[2 * t + 1];
    int ts = d0 + d1;
    // inclusive scan: wave-shuffle within 64 lanes, then tiny cross-wave prefix
    int v = ts;
    #pragma unroll
    for (int o = 1; o < 64; o <<= 1) {
        int u = __shfl_up(v, o, 64);
        if (lane >= o) v += u;
    }
    if (lane == 63) wsum[wv] = v;
    __syncthreads();
    int pre = 0;
    #pragma unroll
    for (int k = 0; k < 4; k++) pre += (k < wv) ? wsum[k] : 0;
    int excl = (v + pre) - ts;
    int na = n0 + 2 * t, nb = n0 + 2 * t + 1;
    tails[2 * t] = eb + excl;
    tails[2 * t + 1] = eb + excl + d0;
    if (na < N) { rowptr[na] = eb + excl;      cnt[na] = d0; dinv[na] = rsqrtf((float)(d0 + 1)); }
    if (nb < N) { rowptr[nb] = eb + excl + d0; cnt[nb] = d1; dinv[nb] = rsqrtf((float)(d1 + 1)); }
    __syncthreads();
    if (fit) {
        int ne4 = ne >> 2;
        for (int l = t; l < ne4; l += 256) {
            uint4 pr = ((const uint4*)ebuf)[l];
            int p0 = atomicAdd(&tails[pr.x & 511], 1); csr[p0] = (int)(pr.x >> DSH);
            int p1 = atomicAdd(&tails[pr.y & 511], 1); csr[p1] = (int)(pr.y >> DSH);
            int p2 = atomicAdd(&tails[pr.z & 511], 1); csr[p2] = (int)(pr.z >> DSH);
            int p3 = atomicAdd(&tails[pr.w & 511], 1); csr[p3] = (int)(pr.w >> DSH);
        }
        for (int l = (ne4 << 2) + t; l < ne; l += 256) {
            unsigned pr = ebuf[l];
            int pos = atomicAdd(&tails[pr & 511], 1);
            csr[pos] = (int)(pr >> DSH);
        }
    } else {
        for (int l = t; l < ne; l += 256) {
            unsigned pr = staged[eb + l];
            int pos = atomicAdd(&tails[pr & 511], 1);
            csr[pos] = (int)(pr >> DSH);
        }
    }
}

// ---------------- GEMM 1 (MFMA): Hb = fp8e4m3((x @ W1) * dinv[row]) ----------------
// R5 one-shot structure (proven): 64-row tile, A (32 KB) + B (32 KB) staged via
// async global_load_lds, one barrier, 2 blocks/CU -> inter-block pipelining.

__global__ __launch_bounds__(256) void k_gemm1(const float* __restrict__ x, const unsigned* __restrict__ W1t,
                                               const float* __restrict__ dinv, unsigned* __restrict__ Hb, int M) {
    __shared__ uint4 As[2048];   // 64 rows x 32 granules (16 B) fp32 = 32 KB
    __shared__ uint4 Bs[2048];   // 128 frag-rows x 16 granules = 32 KB
    int t = threadIdx.x;
    int w = t >> 6, lane = t & 63;
    int m = lane & 15, kg = lane >> 4;
    int blk0 = blockIdx.x * 64;

    // stage A: 2048 granules, pre-swizzled at the global source
    #pragma unroll
    for (int it = 0; it < 8; ++it) {
        int G = it * 256 + t;
        int row = G >> 5, slot = G & 31;
        int rowg = min(blk0 + row, M - 1);
        const float* srcp = x + (size_t)rowg * 128 + ((slot ^ (row & 7)) << 2);
        gload_lds16(srcp, (char*)As + (size_t)G * 16);
    }
    // stage B: 2048 granules
    #pragma unroll
    for (int it = 0; it < 8; ++it) {
        int G = it * 256 + t;
        int rb = G >> 4, slot = G & 15;
        const unsigned* srcp = W1t + rb * 64 + ((slot ^ (rb & 7)) << 2);
        gload_lds16(srcp, (char*)Bs + (size_t)G * 16);
    }
    __syncthreads();   // single drain of all 16 async issues

    int ra = (w << 4) + m;
    int rs = m & 7;
    f32x4 acc[8];
    #pragma unroll
    for (int j = 0; j < 8; j++) acc[j] = (f32x4){0.f, 0.f, 0.f, 0.f};

    #pragma unroll
    for (int ks = 0; ks < 4; ks++) {
        uint4 qa = As[ra * 32 + ((ks * 8 + kg * 2) ^ rs)];
        uint4 qb = As[ra * 32 + ((ks * 8 + kg * 2 + 1) ^ rs)];
        float4 f0 = *(float4*)&qa;
        float4 f1 = *(float4*)&qb;
        U4S8 a0; a0.u = make_uint4(pk_bf16(f0.x, f0.y), pk_bf16(f0.z, f0.w),
                                   pk_bf16(f1.x, f1.y), pk_bf16(f1.z, f1.w));
        #pragma unroll
        for (int nt = 0; nt < 8; nt++) {
            U4S8 b; b.u = Bs[(nt * 16 + m) * 16 + ((ks * 4 + kg) ^ rs)];
            acc[nt] = __builtin_amdgcn_mfma_f32_16x16x32_bf16(a0.s, b.s, acc[nt], 0, 0, 0);
        }
    }
    // C layout: col = lane&15, row = kg*4 + reg. Pack 4 adjacent cols -> 1 uint of fp8.
    int m_base = blk0 + (w << 4);
    #pragma unroll
    for (int r = 0; r < 4; r++) {
        int row = m_base + kg * 4 + r;
        float di = dinv[min(row, M - 1)];
        bool on = (row < M) && ((m & 3) == 0);
        #pragma unroll
        for (int nt = 0; nt < 8; nt++) {
            float v = acc[nt][r] * di;
            float v1 = __shfl_xor(v, 1);
            unsigned wlo = (unsigned)__builtin_amdgcn_cvt_pk_fp8_f32(v, v1, 0, false);
            unsigned whi = __shfl_xor(wlo, 2);
            unsigned u = (wlo & 0xFFFFu) | (whi << 16);
            if (on) Hb[(size_t)row * 32 + nt * 4 + (m >> 2)] = u;
        }
    }
}

// ---------------- Propagation 1: h1b = bf16(relu(dinv[i]*(self + sum_nb) + b1)) ----------------
// ONE node per 16-lane group (4 nodes/wave). Each lane owns 8 features end-to-end.
// 8-deep gather unroll: 8 outstanding 128-B row fetches per group.

__global__ __launch_bounds__(256) void k_prop1(const unsigned* __restrict__ Hb, const int* __restrict__ rowptr,
                                               const int* __restrict__ cnt, const int* __restrict__ csr,
                                               const float* __restrict__ dinv, const float* __restrict__ b1,
                                               unsigned* __restrict__ h1b, int N) {
    int lane = threadIdx.x & 63;
    int g = lane >> 4, q = lane & 15;
    int i = blockIdx.x * 16 + (threadIdx.x >> 6) * 4 + g;
    if (i >= N) return;
    const uint2* H2 = (const uint2*)Hb;    // row = 16 x uint2 (128 B fp8)

    f32x2 a0[4], a1[4], a2[4], a3[4];
    #pragma unroll
    for (int k = 0; k < 4; k++) {
        a0[k] = (f32x2){0.f, 0.f}; a1[k] = (f32x2){0.f, 0.f};
        a2[k] = (f32x2){0.f, 0.f}; a3[k] = (f32x2){0.f, 0.f};
    }

    // self row
    {
        uint2 sv = H2[(size_t)i * 16 + q];
        acc8_fp8(a0, sv);
    }

    int s = rowptr[i];
    int e = s + cnt[i];
    int p = s;
    for (; p + 8 <= e; p += 8) {
        int j0 = csr[p];     int j1 = csr[p + 1];
        int j2 = csr[p + 2]; int j3 = csr[p + 3];
        int j4 = csr[p + 4]; int j5 = csr[p + 5];
        int j6 = csr[p + 6]; int j7 = csr[p + 7];
        uint2 v0 = H2[(size_t)j0 * 16 + q];
        uint2 v1 = H2[(size_t)j1 * 16 + q];
        uint2 v2 = H2[(size_t)j2 * 16 + q];
        uint2 v3 = H2[(size_t)j3 * 16 + q];
        uint2 v4 = H2[(size_t)j4 * 16 + q];
        uint2 v5 = H2[(size_t)j5 * 16 + q];
        uint2 v6 = H2[(size_t)j6 * 16 + q];
        uint2 v7 = H2[(size_t)j7 * 16 + q];
        acc8_fp8(a0, v0); acc8_fp8(a1, v1); acc8_fp8(a2, v2); acc8_fp8(a3, v3);
        acc8_fp8(a0, v4); acc8_fp8(a1, v5); acc8_fp8(a2, v6); acc8_fp8(a3, v7);
    }
    if (p + 4 <= e) {
        int j0 = csr[p];     int j1 = csr[p + 1];
        int j2 = csr[p + 2]; int j3 = csr[p + 3];
        uint2 v0 = H2[(size_t)j0 * 16 + q];
        uint2 v1 = H2[(size_t)j1 * 16 + q];
        uint2 v2 = H2[(size_t)j2 * 16 + q];
        uint2 v3 = H2[(size_t)j3 * 16 + q];
        acc8_fp8(a0, v0); acc8_fp8(a1, v1); acc8_fp8(a2, v2); acc8_fp8(a3, v3);
        p += 4;
    }
    for (; p < e; ++p) {                    // 0..3 leftover edges (exec-masked divergence)
        int j = csr[p];
        uint2 v = H2[(size_t)j * 16 + q];
        acc8_fp8(a0, v);
    }
    #pragma unroll
    for (int k = 0; k < 4; k++) a0[k] = (a0[k] + a1[k]) + (a2[k] + a3[k]);

    float di = dinv[i];
    float4 bA = ((const float4*)b1)[q * 2];
    float4 bB = ((const float4*)b1)[q * 2 + 1];
    float o0 = fmaxf(di * a0[0].x + bA.x, 0.f);
    float o1 = fmaxf(di * a0[0].y + bA.y, 0.f);
    float o2 = fmaxf(di * a0[1].x + bA.z, 0.f);
    float o3 = fmaxf(di * a0[1].y + bA.w, 0.f);
    float o4 = fmaxf(di * a0[2].x + bB.x, 0.f);
    float o5 = fmaxf(di * a0[2].y + bB.y, 0.f);
    float o6 = fmaxf(di * a0[3].x + bB.z, 0.f);
    float o7 = fmaxf(di * a0[3].y + bB.w, 0.f);
    ((uint4*)h1b)[(size_t)i * 16 + q] =
        make_uint4(pk_bf16(o0, o1), pk_bf16(o2, o3), pk_bf16(o4, o5), pk_bf16(o6, o7));
}

// ---------------- GEMM 2 (MFMA): H2b = fp8e4m3((h1 @ W2) * dinv[row]), 40-B rows ----------------
// R5 one-shot structure: async-staged A (16 KB bf16) + B (12 KB).

__global__ __launch_bounds__(256) void k_gemm2(const unsigned* __restrict__ h1b, const unsigned* __restrict__ W2t,
                                               const float* __restrict__ dinv, unsigned* __restrict__ H2b, int M) {
    __shared__ uint4 As[1024];   // 64 rows x 16 granules bf16 = 16 KB
    __shared__ uint4 Bs[768];    // 48 frag-rows x 16 granules = 12 KB
    int t = threadIdx.x;
    int w = t >> 6, lane = t & 63;
    int m = lane & 15, kg = lane >> 4;
    int blk0 = blockIdx.x * 64;

    #pragma unroll
    for (int it = 0; it < 4; ++it) {
        int G = it * 256 + t;
        int row = G >> 4, slot = G & 15;
        int rowg = min(blk0 + row, M - 1);
        const unsigned* srcp = h1b + (size_t)rowg * 64 + ((slot ^ (row & 7)) << 2);
        gload_lds16(srcp, (char*)As + (size_t)G * 16);
    }
    #pragma unroll
    for (int it = 0; it < 3; ++it) {
        int G = it * 256 + t;
        int rb = G >> 4, slot = G & 15;
        const unsigned* srcp = W2t + rb * 64 + ((slot ^ (rb & 7)) << 2);
        gload_lds16(srcp, (char*)Bs + (size_t)G * 16);
    }
    __syncthreads();

    int ra = (w << 4) + m;
    int rs = m & 7;
    f32x4 acc[3];
    #pragma unroll
    for (int j = 0; j < 3; j++) acc[j] = (f32x4){0.f, 0.f, 0.f, 0.f};

    #pragma unroll
    for (int ks = 0; ks < 4; ks++) {
        U4S8 a0; a0.u = As[ra * 16 + ((ks * 4 + kg) ^ rs)];
        #pragma unroll
        for (int nt = 0; nt < 3; nt++) {
            U4S8 b; b.u = Bs[(nt * 16 + m) * 16 + ((ks * 4 + kg) ^ rs)];
            acc[nt] = __builtin_amdgcn_mfma_f32_16x16x32_bf16(a0.s, b.s, acc[nt], 0, 0, 0);
        }
    }
    // pack 8 adjacent cols -> uint2 of fp8; row = 5 uint2 (40 B)
    int m_base = blk0 + (w << 4);
    #pragma unroll
    for (int r = 0; r < 4; r++) {
        int row = m_base + kg * 4 + r;
        float di = dinv[min(row, M - 1)];
        #pragma unroll
        for (int nt = 0; nt < 3; nt++) {
            float v = acc[nt][r] * di;
            float v1 = __shfl_xor(v, 1);
            unsigned wlo = (unsigned)__builtin_amdgcn_cvt_pk_fp8_f32(v, v1, 0, false);
            unsigned whi = __shfl_xor(wlo, 2);
            unsigned u = (wlo & 0xFFFFu) | (whi << 16);
            unsigned u2 = __shfl_xor(u, 4);
            bool on = (row < M) && ((m & 7) == 0) && (nt < 2 || m == 0);
            if (on) ((uint2*)H2b)[(size_t)row * 5 + nt * 2 + (m >> 3)] = make_uint2(u, u2);
        }
    }
}

// ---------------- Propagation 2 + bias + log_softmax -> out ----------------
// ONE node per 5-lane group (12 nodes/wave, lanes 60-63 idle). Each lane owns
// 8 of the 40 features end-to-end; 8-deep gather unroll.

__global__ __launch_bounds__(256) void k_prop2(const unsigned* __restrict__ H2b, const int* __restrict__ rowptr,
                                               const int* __restrict__ cnt, const int* __restrict__ csr,
                                               const float* __restrict__ dinv, const float* __restrict__ b2,
                                               float* __restrict__ out, int N) {
    int lane = threadIdx.x & 63;
    int wv = threadIdx.x >> 6;
    int grp = lane / 5;              // 0..11 active; 12 for lanes 60-63
    int q = lane - grp * 5;          // 0..4
    if (grp >= 12) return;
    int i = blockIdx.x * 48 + wv * 12 + grp;
    if (i >= N) return;              // group-uniform exit (all 5 lanes same i)
    const uint2* H2 = (const uint2*)H2b;   // row = 5 uint2 (40 B)

    f32x2 a0[4], a1[4], a2[4], a3[4];
    #pragma unroll
    for (int k = 0; k < 4; k++) {
        a0[k] = (f32x2){0.f, 0.f}; a1[k] = (f32x2){0.f, 0.f};
        a2[k] = (f32x2){0.f, 0.f}; a3[k] = (f32x2){0.f, 0.f};
    }

    // self row
    acc8_fp8(a0, H2[(size_t)i * 5 + q]);

    int s = rowptr[i];
    int e = s + cnt[i];
    int p = s;
    for (; p + 8 <= e; p += 8) {
        int j0 = csr[p];     int j1 = csr[p + 1];
        int j2 = csr[p + 2]; int j3 = csr[p + 3];
        int j4 = csr[p + 4]; int j5 = csr[p + 5];
        int j6 = csr[p + 6]; int j7 = csr[p + 7];
        uint2 v0 = H2[(size_t)j0 * 5 + q];
        uint2 v1 = H2[(size_t)j1 * 5 + q];
        uint2 v2 = H2[(size_t)j2 * 5 + q];
        uint2 v3 = H2[(size_t)j3 * 5 + q];
        uint2 v4 = H2[(size_t)j4 * 5 + q];
        uint2 v5 = H2[(size_t)j5 * 5 + q];
        uint2 v6 = H2[(size_t)j6 * 5 + q];
        uint2 v7 = H2[(size_t)j7 * 5 + q];
        acc8_fp8(a0, v0); acc8_fp8(a1, v1); acc8_fp8(a2, v2); acc8_fp8(a3, v3);
        acc8_fp8(a0, v4); acc8_fp8(a1, v5); acc8_fp8(a2, v6); acc8_fp8(a3, v7);
    }
    if (p + 4 <= e) {
        int j0 = csr[p];     int j1 = csr[p + 1];
        int j2 = csr[p + 2]; int j3 = csr[p + 3];
        uint2 v0 = H2[(size_t)j0 * 5 + q];
        uint2 v1 = H2[(size_t)j1 * 5 + q];
        uint2 v2 = H2[(size_t)j2 * 5 + q];
        uint2 v3 = H2[(size_t)j3 * 5 + q];
        acc8_fp8(a0, v0); acc8_fp8(a1, v1); acc8_fp8(a2, v2); acc8_fp8(a3, v3);
        p += 4;
    }
    for (; p < e; ++p) {
        uint2 v = H2[(size_t)csr[p] * 5 + q];
        acc8_fp8(a0, v);
    }
    #pragma unroll
    for (int k = 0; k < 4; k++) a0[k] = (a0[k] + a1[k]) + (a2[k] + a3[k]);

    float di = dinv[i];
    float4 b0 = ((const float4*)b2)[q * 2];
    float4 b1v = ((const float4*)b2)[q * 2 + 1];
    float l[8];
    l[0] = di * a0[0].x + b0.x;  l[1] = di * a0[0].y + b0.y;
    l[2] = di * a0[1].x + b0.z;  l[3] = di * a0[1].y + b0.w;
    l[4] = di * a0[2].x + b1v.x; l[5] = di * a0[2].y + b1v.y;
    l[6] = di * a0[3].x + b1v.z; l[7] = di * a0[3].y + b1v.w;

    // local max over 8, then 5-lane group max via +1,+2,+4 (mod 5) tree
    float mx = l[0];
    #pragma unroll
    for (int k = 1; k < 8; k++) mx = fmaxf(mx, l[k]);
    int gb = grp * 5;
    mx = fmaxf(mx, __shfl(mx, gb + (q + 1) % 5));
    mx = fmaxf(mx, __shfl(mx, gb + (q + 2) % 5));
    mx = fmaxf(mx, __shfl(mx, gb + (q + 4) % 5));

    float sm = 0.f;
    #pragma unroll
    for (int k = 0; k < 8; k++) sm += expf(l[k] - mx);
    // 5-lane sum: gather the 4 other lanes' partial sums directly
    float st = sm;
    st += __shfl(sm, gb + (q + 1) % 5);
    st += __shfl(sm, gb + (q + 2) % 5);
    st += __shfl(sm, gb + (q + 3) % 5);
    st += __shfl(sm, gb + (q + 4) % 5);
    float lse = mx + logf(st);

    ((float4*)out)[(size_t)i * 10 + q * 2]     = make_float4(l[0] - lse, l[1] - lse, l[2] - lse, l[3] - lse);
    ((float4*)out)[(size_t)i * 10 + q * 2 + 1] = make_float4(l[4] - lse, l[5] - lse, l[6] - lse, l[7] - lse);
}

// ---------------- launch ----------------

extern "C" void kernel_launch(void* const* d_in, const int* in_sizes, int n_in,
                              void* d_out, int out_size, void* d_ws, size_t ws_size,
                              hipStream_t stream) {
    const float* x  = (const float*)d_in[0];
    const int*   ei = (const int*)d_in[1];
    const float* W1 = (const float*)d_in[2];
    const float* b1 = (const float*)d_in[3];
    const float* W2 = (const float*)d_in[4];
    const float* b2 = (const float*)d_in[5];
    float* out = (float*)d_out;
    char* ws = (char*)d_ws;
    const int N = N_NODES, E = N_EDGES;

    size_t o = 0;
    auto alloc = [&](size_t bytes) { size_t cur = o; o += (bytes + 511) & ~(size_t)511; return cur; };
    int*       cnt    = (int*)(ws + alloc((size_t)N * 4));
    int*       rowptr = (int*)(ws + alloc((size_t)N * 4));
    float*     dinv   = (float*)(ws + alloc((size_t)N * 4));
    int*       gtails = (int*)(ws + alloc((size_t)NBD * 4));
    unsigned*  staged = (unsigned*)(ws + alloc((size_t)NBD * CAP * 4));
    int*       csr    = (int*)(ws + alloc((size_t)NBD * CAP * 4));
    unsigned*  W1t    = (unsigned*)(ws + alloc(128 * 128 * 2));             // bf16 [128][128]
    unsigned*  W2t    = (unsigned*)(ws + alloc(48 * 128 * 2));              // bf16 [48][128]
    unsigned*  Hb     = (unsigned*)(ws + alloc((size_t)(N + 1) * 32 * 4));  // fp8 [N+1,128]
    unsigned*  h1b    = (unsigned*)(ws + alloc((size_t)N * 64 * 4));        // bf16 [N,128]
    unsigned*  H2b    = (unsigned*)(ws + alloc((size_t)(N + 1) * 10 * 4));  // fp8 [N+1,40]

    const int* src = ei;
    const int* dst = ei + E;

    k_prep <<<2, 256, 0, stream>>>(W1, W2, W1t, W2t, Hb, H2b, gtails);
    k_partD<<<NCH, 256, 0, stream>>>(src, dst, gtails, staged, E);
    k_rank <<<NBD, 256, 0, stream>>>(staged, gtails, csr, rowptr, cnt, dinv, N);

    k_gemm1<<<(N + 63) / 64, 256, 0, stream>>>(x, W1t, dinv, Hb, N);
    k_prop1<<<(N + 15) / 16, 256, 0, stream>>>(Hb, rowptr, cnt, csr, dinv, b1, h1b, N);
    k_gemm2<<<(N + 63) / 64, 256, 0, stream>>>(h1b, W2t, dinv, H2b, N);
    k_prop2<<<(N + 47) / 48, 256, 0, stream>>>(H2b, rowptr, cnt, csr, dinv, b2, out, N);

    (void)in_sizes; (void)n_in; (void)out_size; (void)ws_size;
}